// Round 11
// baseline (397.952 us; speedup 1.0000x reference)
//
#include <hip/hip_runtime.h>
#include <cstdint>
#include <cstddef>

#define N_NODES 65536
#define N_EDGES 1048576
#define E_TOT   (N_EDGES + N_NODES)
#define NSLICE  8192                    // N_NODES / 8 XCD slices
#define SCHUNK  ((E_TOT + 255) / 256)   // 4352: 256 chunks per slice

using short8  = __attribute__((ext_vector_type(8))) short;
using floatx4 = __attribute__((ext_vector_type(4))) float;
using half8   = __attribute__((ext_vector_type(8))) _Float16;
using half4   = __attribute__((ext_vector_type(4))) _Float16;
typedef unsigned short ushort_t;

// split fp32 -> bf16 hi (RTN) + bf16 lo (trunc of residual)
__device__ inline void split_bf16(float a, short& hi, short& lo) {
    unsigned u  = __float_as_uint(a);
    unsigned hr = (u + 0x7fffu + ((u >> 16) & 1u)) >> 16;
    float    hf = __uint_as_float(hr << 16);
    hi = (short)hr;
    float    lf = a - hf;
    lo = (short)(__float_as_uint(lf) >> 16);
}

// ---------------- preprocessing ----------------
// deg[] is zeroed via hipMemsetAsync; the +1 self-loop is folded into the scans.

// histogram + pack edges into (src<<16)|dst uint stream
__global__ void k_hist(const int* __restrict__ src, const int* __restrict__ dst,
                       int* __restrict__ deg, unsigned int* __restrict__ ed) {
    int e = blockIdx.x * 256 + threadIdx.x;
    if (e < N_EDGES) {
        int d = __builtin_nontemporal_load(&dst[e]);
        int s = __builtin_nontemporal_load(&src[e]);
        __builtin_nontemporal_store((unsigned int)d | ((unsigned int)s << 16), &ed[e]);
        atomicAdd(&deg[d], 1);
    }
}

__global__ __launch_bounds__(256) void k_scan1(const int* __restrict__ deg, int* __restrict__ off,
                                               int* __restrict__ bsum) {
    __shared__ int sb[256];
    int tid = threadIdx.x;
    int g = blockIdx.x * 256 + tid;
    int v = deg[g] + 1;               // +1: self loop
    sb[tid] = v;
    __syncthreads();
    #pragma unroll
    for (int s = 1; s < 256; s <<= 1) {
        int t = (tid >= s) ? sb[tid - s] : 0;
        __syncthreads();
        sb[tid] += t;
        __syncthreads();
    }
    off[g] = sb[tid] - v;
    if (tid == 255) bsum[blockIdx.x] = sb[255];
}

__global__ __launch_bounds__(256) void k_scan2(int* __restrict__ bsum) {
    __shared__ int sb[256];
    int tid = threadIdx.x;
    int v = bsum[tid];
    sb[tid] = v;
    __syncthreads();
    #pragma unroll
    for (int s = 1; s < 256; s <<= 1) {
        int t = (tid >= s) ? sb[tid - s] : 0;
        __syncthreads();
        sb[tid] += t;
        __syncthreads();
    }
    bsum[tid] = sb[tid] - v;
}

__global__ __launch_bounds__(256) void k_scan3(const int* __restrict__ deg, int* __restrict__ off,
                                               int* __restrict__ cursor, float* __restrict__ dis,
                                               const int* __restrict__ bsum) {
    int tid = threadIdx.x;
    int g = blockIdx.x * 256 + tid;
    int o = off[g] + bsum[blockIdx.x];
    off[g] = o;
    cursor[g] = o;
    dis[g] = rsqrtf((float)(deg[g] + 1));   // +1: self loop
    if (g == 0) off[N_NODES] = E_TOT;
}

// XCD-sliced counting-sort scatter: nt stores bypass per-XCD L2 write-back so
// partially-filled ssort lines merge memory-side instead of ping-ponging.
__global__ void k_scatter(const unsigned int* __restrict__ ed,
                          int* __restrict__ cursor, ushort_t* __restrict__ ssort) {
    int g   = blockIdx.x & 7;
    int blk = blockIdx.x >> 3;
    int lo = g * NSLICE, hi = lo + NSLICE;
    int e0 = blk * SCHUNK;
    int e1 = e0 + SCHUNK; if (e1 > E_TOT) e1 = E_TOT;
    #pragma unroll 2
    for (int e = e0 + threadIdx.x; e < e1; e += 256) {
        int d, s;
        if (e < N_EDGES) {
            unsigned int v = __builtin_nontemporal_load(&ed[e]);
            d = (int)(v & 0xffffu);
            s = (int)(v >> 16);
        } else {
            d = s = e - N_EDGES;
        }
        if (d >= lo && d < hi) {
            int pos = atomicAdd(&cursor[d], 1);
            __builtin_nontemporal_store((ushort_t)s, &ssort[pos]);
        }
    }
}

// ---------------- x -> fp16 rows pre-scaled by dis[row] ----------------

__global__ __launch_bounds__(256) void k_convx(const float* __restrict__ x, const float* __restrict__ dis,
                                               _Float16* __restrict__ xh) {
    int g = blockIdx.x * 256 + threadIdx.x;   // group of 4 elements
    int idx = g * 4;
    int row = idx >> 7;
    float d = dis[row];
    float4 v = *(const float4*)(x + idx);
    half4 o = {(_Float16)(d * v.x), (_Float16)(d * v.y), (_Float16)(d * v.z), (_Float16)(d * v.w)};
    *(half4*)(xh + idx) = o;
}

// ---------------- W1,W2,W3 -> fragment-ordered bf16 hi/lo (single launch) ----------------

__device__ inline void convw_one(const float* W, int K, int N, short* Bh, short* Bl, int g) {
    int lane = g & 63;
    int kt = (g >> 6) % (K / 32);
    int nt = (g >> 6) / (K / 32);
    int n = nt * 16 + (lane & 15);
    int kbase = kt * 32 + (lane >> 4) * 8;
    #pragma unroll
    for (int j = 0; j < 8; ++j) {
        short h, l;
        split_bf16(W[(size_t)(kbase + j) * N + n], h, l);
        Bh[(size_t)g * 8 + j] = h;
        Bl[(size_t)g * 8 + j] = l;
    }
}

#define G1 (16 * 4 * 64)   // W1 128x256
#define G2 (8 * 8 * 64)    // W2 256x128
#define G3 (4 * 4 * 64)    // W3 128x64

__global__ void k_convw3(const float* __restrict__ W1, short* __restrict__ w1h, short* __restrict__ w1l,
                         const float* __restrict__ W2, short* __restrict__ w2h, short* __restrict__ w2l,
                         const float* __restrict__ W3, short* __restrict__ w3h, short* __restrict__ w3l) {
    int g = blockIdx.x * 256 + threadIdx.x;
    if (g < G1)            convw_one(W1, 128, 256, w1h, w1l, g);
    else if (g < G1 + G2)  convw_one(W2, 256, 128, w2h, w2l, g - G1);
    else if (g < G1 + G2 + G3) convw_one(W3, 128, 64, w3h, w3l, g - G1 - G2);
}

// ---------------- split-bf16 MFMA GEMM: C[M,N] = A[M,K] @ W ----------------
// A is fp16 rows. ACT: C = softmax(relu(C + bias)) -> fp16.
// else: C = dis[row] * C -> fp16 (feeds the gather).

template <int K, int N, bool ACT>
__global__ __launch_bounds__(256) void k_mm(const _Float16* __restrict__ A,
                                            const short* __restrict__ Bh, const short* __restrict__ Bl,
                                            const float* __restrict__ bias, const float* __restrict__ dis,
                                            _Float16* __restrict__ Cout) {
    constexpr int NT = N / 16;
    constexpr int KT = K / 32;
    __shared__ short Ah[4 * 64 * 8];
    __shared__ short Al[4 * 64 * 8];
    int tid = threadIdx.x;
    int wave = tid >> 6, lane = tid & 63;
    int quad = lane >> 4, col = lane & 15;
    size_t row0 = (size_t)blockIdx.x * 64;

    floatx4 acc[NT];
    #pragma unroll
    for (int t = 0; t < NT; ++t) acc[t] = (floatx4)0.0f;

    int srow = tid >> 2;
    int sdst = ((srow >> 4) * 64 + (srow & 15) + ((tid & 3) << 4)) * 8;
    const _Float16* arow = A + (row0 + srow) * K + (tid & 3) * 8;

    for (int kt = 0; kt < KT; ++kt) {
        half8 a8 = *(const half8*)(arow + kt * 32);
        short h[8], l[8];
        #pragma unroll
        for (int j = 0; j < 8; ++j) split_bf16((float)a8[j], h[j], l[j]);
        __syncthreads();
        *(short8*)(&Ah[sdst]) = *(short8*)h;
        *(short8*)(&Al[sdst]) = *(short8*)l;
        __syncthreads();
        short8 afh = *(short8*)(&Ah[(wave * 64 + lane) * 8]);
        short8 afl = *(short8*)(&Al[(wave * 64 + lane) * 8]);
        #pragma unroll
        for (int nt = 0; nt < NT; ++nt) {
            size_t bi = ((size_t)(nt * KT + kt) * 64 + lane);
            short8 bfh = ((const short8*)Bh)[bi];
            short8 bfl = ((const short8*)Bl)[bi];
            acc[nt] = __builtin_amdgcn_mfma_f32_16x16x32_bf16(afh, bfh, acc[nt], 0, 0, 0);
            acc[nt] = __builtin_amdgcn_mfma_f32_16x16x32_bf16(afh, bfl, acc[nt], 0, 0, 0);
            acc[nt] = __builtin_amdgcn_mfma_f32_16x16x32_bf16(afl, bfh, acc[nt], 0, 0, 0);
        }
    }

    size_t rbase = row0 + wave * 16 + quad * 4;
    if (!ACT) {
        float4 d4 = *(const float4*)(dis + rbase);
        float dr[4] = {d4.x, d4.y, d4.z, d4.w};
        #pragma unroll
        for (int nt = 0; nt < NT; ++nt)
            #pragma unroll
            for (int r = 0; r < 4; ++r)
                Cout[(rbase + r) * N + nt * 16 + col] = (_Float16)(acc[nt][r] * dr[r]);
    } else {
        float bv[NT];
        #pragma unroll
        for (int nt = 0; nt < NT; ++nt) bv[nt] = bias[nt * 16 + col];
        float mr[4] = {0.f, 0.f, 0.f, 0.f};
        #pragma unroll
        for (int nt = 0; nt < NT; ++nt)
            #pragma unroll
            for (int r = 0; r < 4; ++r) {
                float v = fmaxf(acc[nt][r] + bv[nt], 0.0f);
                acc[nt][r] = v;
                mr[r] = fmaxf(mr[r], v);
            }
        #pragma unroll
        for (int mask = 1; mask < 16; mask <<= 1)
            #pragma unroll
            for (int r = 0; r < 4; ++r) mr[r] = fmaxf(mr[r], __shfl_xor(mr[r], mask, 64));
        float sr[4] = {0.f, 0.f, 0.f, 0.f};
        #pragma unroll
        for (int nt = 0; nt < NT; ++nt)
            #pragma unroll
            for (int r = 0; r < 4; ++r) {
                float t = __expf(acc[nt][r] - mr[r]);
                acc[nt][r] = t;
                sr[r] += t;
            }
        #pragma unroll
        for (int mask = 1; mask < 16; mask <<= 1)
            #pragma unroll
            for (int r = 0; r < 4; ++r) sr[r] += __shfl_xor(sr[r], mask, 64);
        float inv[4];
        #pragma unroll
        for (int r = 0; r < 4; ++r) inv[r] = 1.0f / sr[r];
        #pragma unroll
        for (int nt = 0; nt < NT; ++nt)
            #pragma unroll
            for (int r = 0; r < 4; ++r)
                Cout[(rbase + r) * N + nt * 16 + col] = (_Float16)(acc[nt][r] * inv[r]);
    }
}

// ---------------- aggregation, DOUT=128, fp16 rows: quarter-wave (16 lanes x 16B) per edge ----------------
// gather pairs combined with packed fp16 adds (4 v_pk_add_f16) before one fp32 cvt+add chain.

template <bool ACT>
__global__ __launch_bounds__(256) void k_agg128h(const _Float16* __restrict__ h, const int* __restrict__ off,
                                                 const ushort_t* __restrict__ ss, const float* __restrict__ dis,
                                                 const float* __restrict__ bias, _Float16* __restrict__ out) {
    int lane = threadIdx.x & 63;
    int sub = lane >> 4;      // 0..3: edge slot
    int li  = lane & 15;      // column group: halfs [li*8, li*8+8)
    int c0  = li * 8;
    int n = blockIdx.x * 4 + (threadIdx.x >> 6);
    int e0 = off[n], e1 = off[n + 1];
    int e = e0;
    float acc[8];
    #pragma unroll
    for (int j = 0; j < 8; ++j) acc[j] = 0.0f;

    for (; e + 8 <= e1; e += 8) {
        int sa = ss[e + sub];
        int sb = ss[e + 4 + sub];
        half8 va = *(const half8*)(h + (size_t)sa * 128 + c0);
        half8 vb = *(const half8*)(h + (size_t)sb * 128 + c0);
        half8 vs = va + vb;   // packed fp16 pair-combine
        #pragma unroll
        for (int j = 0; j < 8; ++j) acc[j] += (float)vs[j];
    }
    while (e < e1) {
        int rem = e1 - e;
        int idx = e + sub;
        if (idx >= e1) idx = e1 - 1;
        int s = ss[idx];
        half8 v = *(const half8*)(h + (size_t)s * 128 + c0);
        float w = (sub < rem) ? 1.0f : 0.0f;
        #pragma unroll
        for (int j = 0; j < 8; ++j) acc[j] = fmaf(w, (float)v[j], acc[j]);
        e += 4;
    }

    #pragma unroll
    for (int mask = 32; mask >= 16; mask >>= 1)
        #pragma unroll
        for (int j = 0; j < 8; ++j) acc[j] += __shfl_xor(acc[j], mask, 64);

    float dn = dis[n];
    if (ACT) {
        float m = 0.0f;
        #pragma unroll
        for (int j = 0; j < 8; ++j) {
            float v = fmaxf(fmaf(acc[j], dn, bias[c0 + j]), 0.0f);
            acc[j] = v;
            m = fmaxf(m, v);
        }
        #pragma unroll
        for (int mask = 8; mask > 0; mask >>= 1) m = fmaxf(m, __shfl_xor(m, mask, 64));
        float sum = 0.0f;
        #pragma unroll
        for (int j = 0; j < 8; ++j) {
            float t = __expf(acc[j] - m);
            acc[j] = t;
            sum += t;
        }
        #pragma unroll
        for (int mask = 8; mask > 0; mask >>= 1) sum += __shfl_xor(sum, mask, 64);
        float inv = 1.0f / sum;
        #pragma unroll
        for (int j = 0; j < 8; ++j) acc[j] *= inv;
    } else {
        #pragma unroll
        for (int j = 0; j < 8; ++j) acc[j] *= dn;
    }
    if (sub == 0) {
        half8 o;
        #pragma unroll
        for (int j = 0; j < 8; ++j) o[j] = (_Float16)acc[j];
        *(half8*)(out + (size_t)n * 128 + c0) = o;
    }
}

// ---------------- aggregation, DOUT=64, fp16 rows: eighth-wave (8 lanes x 16B) per edge ----------------

__global__ __launch_bounds__(256) void k_agg64h(const _Float16* __restrict__ h, const int* __restrict__ off,
                                                const ushort_t* __restrict__ ss, const float* __restrict__ dis,
                                                const float* __restrict__ bias, float* __restrict__ out) {
    int lane = threadIdx.x & 63;
    int sub = lane >> 3;      // 0..7: edge slot
    int li  = lane & 7;       // column group: halfs [li*8, li*8+8)
    int c0  = li * 8;
    int n = blockIdx.x * 4 + (threadIdx.x >> 6);
    int e0 = off[n], e1 = off[n + 1];
    int e = e0;
    float acc[8];
    #pragma unroll
    for (int j = 0; j < 8; ++j) acc[j] = 0.0f;

    for (; e + 8 <= e1; e += 8) {
        int s = ss[e + sub];
        half8 v = *(const half8*)(h + (size_t)s * 64 + c0);
        #pragma unroll
        for (int j = 0; j < 8; ++j) acc[j] += (float)v[j];
    }
    int rem = e1 - e;
    if (rem > 0) {
        int idx = e + sub;
        if (idx >= e1) idx = e1 - 1;
        int s = ss[idx];
        half8 v = *(const half8*)(h + (size_t)s * 64 + c0);
        float w = (sub < rem) ? 1.0f : 0.0f;
        #pragma unroll
        for (int j = 0; j < 8; ++j) acc[j] = fmaf(w, (float)v[j], acc[j]);
    }

    #pragma unroll
    for (int mask = 32; mask >= 8; mask >>= 1)
        #pragma unroll
        for (int j = 0; j < 8; ++j) acc[j] += __shfl_xor(acc[j], mask, 64);

    float dn = dis[n];
    float m = 0.0f;
    #pragma unroll
    for (int j = 0; j < 8; ++j) {
        float v = fmaxf(fmaf(acc[j], dn, bias[c0 + j]), 0.0f);
        acc[j] = v;
        m = fmaxf(m, v);
    }
    #pragma unroll
    for (int mask = 4; mask > 0; mask >>= 1) m = fmaxf(m, __shfl_xor(m, mask, 64));
    float sum = 0.0f;
    #pragma unroll
    for (int j = 0; j < 8; ++j) {
        float t = __expf(acc[j] - m);
        acc[j] = t;
        sum += t;
    }
    #pragma unroll
    for (int mask = 4; mask > 0; mask >>= 1) sum += __shfl_xor(sum, mask, 64);
    float inv = 1.0f / sum;
    if (sub == 0) {
        float* op = out + (size_t)n * 64 + c0;
        *(float4*)(op)     = make_float4(acc[0] * inv, acc[1] * inv, acc[2] * inv, acc[3] * inv);
        *(float4*)(op + 4) = make_float4(acc[4] * inv, acc[5] * inv, acc[6] * inv, acc[7] * inv);
    }
}

// ---------------- launch ----------------

extern "C" void kernel_launch(void* const* d_in, const int* in_sizes, int n_in,
                              void* d_out, int out_size, void* d_ws, size_t ws_size,
                              hipStream_t stream) {
    const float* x  = (const float*)d_in[0];
    const int*   ei = (const int*)d_in[1];
    const float* W1 = (const float*)d_in[2];
    const float* b1 = (const float*)d_in[3];
    const float* W2 = (const float*)d_in[4];
    const float* b2 = (const float*)d_in[5];
    const float* W3 = (const float*)d_in[6];
    const float* b3 = (const float*)d_in[7];
    const int* srcE = ei;
    const int* dstE = ei + N_EDGES;

    char* p = (char*)d_ws;
    auto carve = [&](size_t bytes) {
        char* q = p;
        p += (bytes + 255) & ~(size_t)255;
        return q;
    };
    int*          deg   = (int*)carve(sizeof(int) * N_NODES);
    int*          cur   = (int*)carve(sizeof(int) * N_NODES);
    int*          off   = (int*)carve(sizeof(int) * (N_NODES + 1));
    float*        dis   = (float*)carve(sizeof(float) * N_NODES);
    int*          bsum  = (int*)carve(sizeof(int) * 256);
    unsigned int* ed    = (unsigned int*)carve(sizeof(unsigned int) * N_EDGES);
    ushort_t*     ssort = (ushort_t*)carve(sizeof(ushort_t) * E_TOT);
    short*        w1h   = (short*)carve(sizeof(short) * 128 * 256);
    short*        w1l   = (short*)carve(sizeof(short) * 128 * 256);
    short*        w2h   = (short*)carve(sizeof(short) * 256 * 128);
    short*        w2l   = (short*)carve(sizeof(short) * 256 * 128);
    short*        w3h   = (short*)carve(sizeof(short) * 128 * 64);
    short*        w3l   = (short*)carve(sizeof(short) * 128 * 64);
    _Float16*     xh    = (_Float16*)carve(sizeof(_Float16) * (size_t)N_NODES * 128);
    _Float16*     a0h   = (_Float16*)carve(sizeof(_Float16) * (size_t)N_NODES * 128);
    _Float16*     x1h   = (_Float16*)carve(sizeof(_Float16) * (size_t)N_NODES * 256);
    _Float16*     x2h   = (_Float16*)carve(sizeof(_Float16) * (size_t)N_NODES * 128);
    _Float16*     hh    = (_Float16*)carve(sizeof(_Float16) * (size_t)N_NODES * 128);  // h2' then h3'

    hipMemsetAsync(deg, 0, sizeof(int) * N_NODES, stream);
    k_hist<<<(N_EDGES + 255) / 256, 256, 0, stream>>>(srcE, dstE, deg, ed);
    k_scan1<<<N_NODES / 256, 256, 0, stream>>>(deg, off, bsum);
    k_scan2<<<1, 256, 0, stream>>>(bsum);
    k_scan3<<<N_NODES / 256, 256, 0, stream>>>(deg, off, cur, dis, bsum);
    k_scatter<<<2048, 256, 0, stream>>>(ed, cur, ssort);
    k_convx<<<(N_NODES * 128 / 4) / 256, 256, 0, stream>>>(x, dis, xh);
    k_convw3<<<(G1 + G2 + G3 + 255) / 256, 256, 0, stream>>>(W1, w1h, w1l, W2, w2h, w2l, W3, w3h, w3l);

    // layer 1 (agg-first): a0[n] = dis[n] * sum xh[src]  (xh pre-scaled by dis[src]), fp16
    k_agg128h<false><<<N_NODES / 4, 256, 0, stream>>>(xh, off, ssort, dis, nullptr, a0h);
    // x1 = softmax(relu(a0@W1 + b1)), fp16
    k_mm<128, 256, true><<<N_NODES / 64, 256, 0, stream>>>(a0h, w1h, w1l, b1, nullptr, x1h);
    // layer 2: h2' = fp16(dis .* (x1@W2)); x2 = softmax(relu(dis[n]*segsum(h2') + b2)), fp16
    k_mm<256, 128, false><<<N_NODES / 64, 256, 0, stream>>>(x1h, w2h, w2l, nullptr, dis, hh);
    k_agg128h<true><<<N_NODES / 4, 256, 0, stream>>>(hh, off, ssort, dis, b2, x2h);
    // layer 3: h3' = fp16(dis .* (x2@W3)); out = softmax(relu(dis[n]*segsum(h3') + b3)), fp32
    k_mm<128, 64, false><<<N_NODES / 64, 256, 0, stream>>>(x2h, w3h, w3l, nullptr, dis, hh);
    k_agg64h<<<N_NODES / 4, 256, 0, stream>>>(hh, off, ssort, dis, b3, (float*)d_out);
}

// Round 13
// 364.712 us; speedup vs baseline: 1.0911x; 1.0911x over previous
//
#include <hip/hip_runtime.h>
#include <cstdint>
#include <cstddef>

#define N_NODES 65536
#define N_EDGES 1048576
#define E_TOT   (N_EDGES + N_NODES)

using short8  = __attribute__((ext_vector_type(8))) short;
using floatx4 = __attribute__((ext_vector_type(4))) float;
using half8   = __attribute__((ext_vector_type(8))) _Float16;
using half4   = __attribute__((ext_vector_type(4))) _Float16;
typedef unsigned short ushort_t;
typedef unsigned long long u64;

// split fp32 -> bf16 hi (RTN) + bf16 lo (trunc of residual)
__device__ inline void split_bf16(float a, short& hi, short& lo) {
    unsigned u  = __float_as_uint(a);
    unsigned hr = (u + 0x7fffu + ((u >> 16) & 1u)) >> 16;
    float    hf = __uint_as_float(hr << 16);
    hi = (short)hr;
    float    lf = a - hf;
    lo = (short)(__float_as_uint(lf) >> 16);
}

// ---------------- preprocessing ----------------
// deg[] zeroed via hipMemsetAsync. Self-loop handled outside the edge stream.

// histogram + deterministic rank capture: ed2[e] = rank<<32 | (s<<16) | d
__global__ void k_hist(const int* __restrict__ src, const int* __restrict__ dst,
                       int* __restrict__ deg, u64* __restrict__ ed2) {
    int e = blockIdx.x * 256 + threadIdx.x;
    if (e < N_EDGES) {
        int d = __builtin_nontemporal_load(&dst[e]);
        int s = __builtin_nontemporal_load(&src[e]);
        int rank = atomicAdd(&deg[d], 1);
        u64 rec = ((u64)(unsigned)rank << 32) | (u64)((unsigned)d | ((unsigned)s << 16));
        __builtin_nontemporal_store(rec, &ed2[e]);
    }
}

__global__ __launch_bounds__(256) void k_scan1(const int* __restrict__ deg, int* __restrict__ off,
                                               int* __restrict__ bsum) {
    __shared__ int sb[256];
    int tid = threadIdx.x;
    int g = blockIdx.x * 256 + tid;
    int v = deg[g] + 1;               // +1: self loop
    sb[tid] = v;
    __syncthreads();
    #pragma unroll
    for (int s = 1; s < 256; s <<= 1) {
        int t = (tid >= s) ? sb[tid - s] : 0;
        __syncthreads();
        sb[tid] += t;
        __syncthreads();
    }
    off[g] = sb[tid] - v;
    if (tid == 255) bsum[blockIdx.x] = sb[255];
}

__global__ __launch_bounds__(256) void k_scan2(int* __restrict__ bsum) {
    __shared__ int sb[256];
    int tid = threadIdx.x;
    int v = bsum[tid];
    sb[tid] = v;
    __syncthreads();
    #pragma unroll
    for (int s = 1; s < 256; s <<= 1) {
        int t = (tid >= s) ? sb[tid - s] : 0;
        __syncthreads();
        sb[tid] += t;
        __syncthreads();
    }
    bsum[tid] = sb[tid] - v;
}

// finalize offsets, dis, and place the self-loop edge at the end of each segment
__global__ __launch_bounds__(256) void k_scan3(const int* __restrict__ deg, int* __restrict__ off,
                                               float* __restrict__ dis, const int* __restrict__ bsum,
                                               ushort_t* __restrict__ ssort) {
    int tid = threadIdx.x;
    int g = blockIdx.x * 256 + tid;
    int d = deg[g];
    int o = off[g] + bsum[blockIdx.x];
    off[g] = o;
    dis[g] = rsqrtf((float)(d + 1));        // +1: self loop
    ssort[o + d] = (ushort_t)g;             // self loop at segment end
    if (g == 0) off[N_NODES] = E_TOT;
}

// atomic-free scatter: slot = off[d] + rank (rank captured in k_hist)
__global__ void k_scatter(const u64* __restrict__ ed2, const int* __restrict__ off,
                          ushort_t* __restrict__ ssort) {
    int e = blockIdx.x * 256 + threadIdx.x;
    if (e >= N_EDGES) return;
    u64 v = __builtin_nontemporal_load(&ed2[e]);
    int d = (int)(v & 0xffffu);
    int s = (int)((v >> 16) & 0xffffu);
    int rank = (int)(v >> 32);
    ssort[off[d] + rank] = (ushort_t)s;
}

// ---------------- x -> fp16 rows pre-scaled by dis[row] ----------------

__global__ __launch_bounds__(256) void k_convx(const float* __restrict__ x, const float* __restrict__ dis,
                                               _Float16* __restrict__ xh) {
    int g = blockIdx.x * 256 + threadIdx.x;   // group of 4 elements
    int idx = g * 4;
    int row = idx >> 7;
    float d = dis[row];
    float4 v = *(const float4*)(x + idx);
    half4 o = {(_Float16)(d * v.x), (_Float16)(d * v.y), (_Float16)(d * v.z), (_Float16)(d * v.w)};
    *(half4*)(xh + idx) = o;
}

// ---------------- W1,W2,W3 -> fragment-ordered bf16 hi/lo (single launch) ----------------

__device__ inline void convw_one(const float* W, int K, int N, short* Bh, short* Bl, int g) {
    int lane = g & 63;
    int kt = (g >> 6) % (K / 32);
    int nt = (g >> 6) / (K / 32);
    int n = nt * 16 + (lane & 15);
    int kbase = kt * 32 + (lane >> 4) * 8;
    #pragma unroll
    for (int j = 0; j < 8; ++j) {
        short h, l;
        split_bf16(W[(size_t)(kbase + j) * N + n], h, l);
        Bh[(size_t)g * 8 + j] = h;
        Bl[(size_t)g * 8 + j] = l;
    }
}

#define G1 (16 * 4 * 64)   // W1 128x256
#define G2 (8 * 8 * 64)    // W2 256x128
#define G3 (4 * 4 * 64)    // W3 128x64

__global__ void k_convw3(const float* __restrict__ W1, short* __restrict__ w1h, short* __restrict__ w1l,
                         const float* __restrict__ W2, short* __restrict__ w2h, short* __restrict__ w2l,
                         const float* __restrict__ W3, short* __restrict__ w3h, short* __restrict__ w3l) {
    int g = blockIdx.x * 256 + threadIdx.x;
    if (g < G1)            convw_one(W1, 128, 256, w1h, w1l, g);
    else if (g < G1 + G2)  convw_one(W2, 256, 128, w2h, w2l, g - G1);
    else if (g < G1 + G2 + G3) convw_one(W3, 128, 64, w3h, w3l, g - G1 - G2);
}

// ---------------- split-bf16 MFMA GEMM: C[M,N] = A[M,K] @ W ----------------
// A is fp16 rows. ACT: C = softmax(relu(C + bias)) -> fp16.
// else: C = dis[row] * C -> fp16 (feeds the gather).

template <int K, int N, bool ACT>
__global__ __launch_bounds__(256) void k_mm(const _Float16* __restrict__ A,
                                            const short* __restrict__ Bh, const short* __restrict__ Bl,
                                            const float* __restrict__ bias, const float* __restrict__ dis,
                                            _Float16* __restrict__ Cout) {
    constexpr int NT = N / 16;
    constexpr int KT = K / 32;
    __shared__ short Ah[4 * 64 * 8];
    __shared__ short Al[4 * 64 * 8];
    int tid = threadIdx.x;
    int wave = tid >> 6, lane = tid & 63;
    int quad = lane >> 4, col = lane & 15;
    size_t row0 = (size_t)blockIdx.x * 64;

    floatx4 acc[NT];
    #pragma unroll
    for (int t = 0; t < NT; ++t) acc[t] = (floatx4)0.0f;

    int srow = tid >> 2;
    int sdst = ((srow >> 4) * 64 + (srow & 15) + ((tid & 3) << 4)) * 8;
    const _Float16* arow = A + (row0 + srow) * K + (tid & 3) * 8;

    for (int kt = 0; kt < KT; ++kt) {
        half8 a8 = *(const half8*)(arow + kt * 32);
        short h[8], l[8];
        #pragma unroll
        for (int j = 0; j < 8; ++j) split_bf16((float)a8[j], h[j], l[j]);
        __syncthreads();
        *(short8*)(&Ah[sdst]) = *(short8*)h;
        *(short8*)(&Al[sdst]) = *(short8*)l;
        __syncthreads();
        short8 afh = *(short8*)(&Ah[(wave * 64 + lane) * 8]);
        short8 afl = *(short8*)(&Al[(wave * 64 + lane) * 8]);
        #pragma unroll
        for (int nt = 0; nt < NT; ++nt) {
            size_t bi = ((size_t)(nt * KT + kt) * 64 + lane);
            short8 bfh = ((const short8*)Bh)[bi];
            short8 bfl = ((const short8*)Bl)[bi];
            acc[nt] = __builtin_amdgcn_mfma_f32_16x16x32_bf16(afh, bfh, acc[nt], 0, 0, 0);
            acc[nt] = __builtin_amdgcn_mfma_f32_16x16x32_bf16(afh, bfl, acc[nt], 0, 0, 0);
            acc[nt] = __builtin_amdgcn_mfma_f32_16x16x32_bf16(afl, bfh, acc[nt], 0, 0, 0);
        }
    }

    size_t rbase = row0 + wave * 16 + quad * 4;
    if (!ACT) {
        float4 d4 = *(const float4*)(dis + rbase);
        float dr[4] = {d4.x, d4.y, d4.z, d4.w};
        #pragma unroll
        for (int nt = 0; nt < NT; ++nt)
            #pragma unroll
            for (int r = 0; r < 4; ++r)
                Cout[(rbase + r) * N + nt * 16 + col] = (_Float16)(acc[nt][r] * dr[r]);
    } else {
        float bv[NT];
        #pragma unroll
        for (int nt = 0; nt < NT; ++nt) bv[nt] = bias[nt * 16 + col];
        float mr[4] = {0.f, 0.f, 0.f, 0.f};
        #pragma unroll
        for (int nt = 0; nt < NT; ++nt)
            #pragma unroll
            for (int r = 0; r < 4; ++r) {
                float v = fmaxf(acc[nt][r] + bv[nt], 0.0f);
                acc[nt][r] = v;
                mr[r] = fmaxf(mr[r], v);
            }
        #pragma unroll
        for (int mask = 1; mask < 16; mask <<= 1)
            #pragma unroll
            for (int r = 0; r < 4; ++r) mr[r] = fmaxf(mr[r], __shfl_xor(mr[r], mask, 64));
        float sr[4] = {0.f, 0.f, 0.f, 0.f};
        #pragma unroll
        for (int nt = 0; nt < NT; ++nt)
            #pragma unroll
            for (int r = 0; r < 4; ++r) {
                float t = __expf(acc[nt][r] - mr[r]);
                acc[nt][r] = t;
                sr[r] += t;
            }
        #pragma unroll
        for (int mask = 1; mask < 16; mask <<= 1)
            #pragma unroll
            for (int r = 0; r < 4; ++r) sr[r] += __shfl_xor(sr[r], mask, 64);
        float inv[4];
        #pragma unroll
        for (int r = 0; r < 4; ++r) inv[r] = 1.0f / sr[r];
        #pragma unroll
        for (int nt = 0; nt < NT; ++nt)
            #pragma unroll
            for (int r = 0; r < 4; ++r)
                Cout[(rbase + r) * N + nt * 16 + col] = (_Float16)(acc[nt][r] * inv[r]);
    }
}

// ---------------- aggregation, DOUT=128, fp16 rows: quarter-wave (16 lanes x 16B) per edge ----------------
// gather pairs combined with packed fp16 adds before one fp32 cvt+add chain.

template <bool ACT>
__global__ __launch_bounds__(256) void k_agg128h(const _Float16* __restrict__ h, const int* __restrict__ off,
                                                 const ushort_t* __restrict__ ss, const float* __restrict__ dis,
                                                 const float* __restrict__ bias, _Float16* __restrict__ out) {
    int lane = threadIdx.x & 63;
    int sub = lane >> 4;      // 0..3: edge slot
    int li  = lane & 15;      // column group: halfs [li*8, li*8+8)
    int c0  = li * 8;
    int n = blockIdx.x * 4 + (threadIdx.x >> 6);
    int e0 = off[n], e1 = off[n + 1];
    int e = e0;
    float acc[8];
    #pragma unroll
    for (int j = 0; j < 8; ++j) acc[j] = 0.0f;

    for (; e + 8 <= e1; e += 8) {
        int sa = ss[e + sub];
        int sb = ss[e + 4 + sub];
        half8 va = *(const half8*)(h + (size_t)sa * 128 + c0);
        half8 vb = *(const half8*)(h + (size_t)sb * 128 + c0);
        half8 vs = va + vb;   // packed fp16 pair-combine
        #pragma unroll
        for (int j = 0; j < 8; ++j) acc[j] += (float)vs[j];
    }
    while (e < e1) {
        int rem = e1 - e;
        int idx = e + sub;
        if (idx >= e1) idx = e1 - 1;
        int s = ss[idx];
        half8 v = *(const half8*)(h + (size_t)s * 128 + c0);
        float w = (sub < rem) ? 1.0f : 0.0f;
        #pragma unroll
        for (int j = 0; j < 8; ++j) acc[j] = fmaf(w, (float)v[j], acc[j]);
        e += 4;
    }

    #pragma unroll
    for (int mask = 32; mask >= 16; mask >>= 1)
        #pragma unroll
        for (int j = 0; j < 8; ++j) acc[j] += __shfl_xor(acc[j], mask, 64);

    float dn = dis[n];
    if (ACT) {
        float m = 0.0f;
        #pragma unroll
        for (int j = 0; j < 8; ++j) {
            float v = fmaxf(fmaf(acc[j], dn, bias[c0 + j]), 0.0f);
            acc[j] = v;
            m = fmaxf(m, v);
        }
        #pragma unroll
        for (int mask = 8; mask > 0; mask >>= 1) m = fmaxf(m, __shfl_xor(m, mask, 64));
        float sum = 0.0f;
        #pragma unroll
        for (int j = 0; j < 8; ++j) {
            float t = __expf(acc[j] - m);
            acc[j] = t;
            sum += t;
        }
        #pragma unroll
        for (int mask = 8; mask > 0; mask >>= 1) sum += __shfl_xor(sum, mask, 64);
        float inv = 1.0f / sum;
        #pragma unroll
        for (int j = 0; j < 8; ++j) acc[j] *= inv;
    } else {
        #pragma unroll
        for (int j = 0; j < 8; ++j) acc[j] *= dn;
    }
    if (sub == 0) {
        half8 o;
        #pragma unroll
        for (int j = 0; j < 8; ++j) o[j] = (_Float16)acc[j];
        *(half8*)(out + (size_t)n * 128 + c0) = o;
    }
}

// ---------------- aggregation, DOUT=64, fp16 rows: eighth-wave (8 lanes x 16B) per edge ----------------

__global__ __launch_bounds__(256) void k_agg64h(const _Float16* __restrict__ h, const int* __restrict__ off,
                                                const ushort_t* __restrict__ ss, const float* __restrict__ dis,
                                                const float* __restrict__ bias, float* __restrict__ out) {
    int lane = threadIdx.x & 63;
    int sub = lane >> 3;      // 0..7: edge slot
    int li  = lane & 7;       // column group: halfs [li*8, li*8+8)
    int c0  = li * 8;
    int n = blockIdx.x * 4 + (threadIdx.x >> 6);
    int e0 = off[n], e1 = off[n + 1];
    int e = e0;
    float acc[8];
    #pragma unroll
    for (int j = 0; j < 8; ++j) acc[j] = 0.0f;

    for (; e + 8 <= e1; e += 8) {
        int s = ss[e + sub];
        half8 v = *(const half8*)(h + (size_t)s * 64 + c0);
        #pragma unroll
        for (int j = 0; j < 8; ++j) acc[j] += (float)v[j];
    }
    int rem = e1 - e;
    if (rem > 0) {
        int idx = e + sub;
        if (idx >= e1) idx = e1 - 1;
        int s = ss[idx];
        half8 v = *(const half8*)(h + (size_t)s * 64 + c0);
        float w = (sub < rem) ? 1.0f : 0.0f;
        #pragma unroll
        for (int j = 0; j < 8; ++j) acc[j] = fmaf(w, (float)v[j], acc[j]);
    }

    #pragma unroll
    for (int mask = 32; mask >= 8; mask >>= 1)
        #pragma unroll
        for (int j = 0; j < 8; ++j) acc[j] += __shfl_xor(acc[j], mask, 64);

    float dn = dis[n];
    float m = 0.0f;
    #pragma unroll
    for (int j = 0; j < 8; ++j) {
        float v = fmaxf(fmaf(acc[j], dn, bias[c0 + j]), 0.0f);
        acc[j] = v;
        m = fmaxf(m, v);
    }
    #pragma unroll
    for (int mask = 4; mask > 0; mask >>= 1) m = fmaxf(m, __shfl_xor(m, mask, 64));
    float sum = 0.0f;
    #pragma unroll
    for (int j = 0; j < 8; ++j) {
        float t = __expf(acc[j] - m);
        acc[j] = t;
        sum += t;
    }
    #pragma unroll
    for (int mask = 4; mask > 0; mask >>= 1) sum += __shfl_xor(sum, mask, 64);
    float inv = 1.0f / sum;
    if (sub == 0) {
        float* op = out + (size_t)n * 64 + c0;
        *(float4*)(op)     = make_float4(acc[0] * inv, acc[1] * inv, acc[2] * inv, acc[3] * inv);
        *(float4*)(op + 4) = make_float4(acc[4] * inv, acc[5] * inv, acc[6] * inv, acc[7] * inv);
    }
}

// ---------------- launch ----------------

extern "C" void kernel_launch(void* const* d_in, const int* in_sizes, int n_in,
                              void* d_out, int out_size, void* d_ws, size_t ws_size,
                              hipStream_t stream) {
    const float* x  = (const float*)d_in[0];
    const int*   ei = (const int*)d_in[1];
    const float* W1 = (const float*)d_in[2];
    const float* b1 = (const float*)d_in[3];
    const float* W2 = (const float*)d_in[4];
    const float* b2 = (const float*)d_in[5];
    const float* W3 = (const float*)d_in[6];
    const float* b3 = (const float*)d_in[7];
    const int* srcE = ei;
    const int* dstE = ei + N_EDGES;

    char* p = (char*)d_ws;
    auto carve = [&](size_t bytes) {
        char* q = p;
        p += (bytes + 255) & ~(size_t)255;
        return q;
    };
    int*          deg   = (int*)carve(sizeof(int) * N_NODES);
    int*          off   = (int*)carve(sizeof(int) * (N_NODES + 1));
    float*        dis   = (float*)carve(sizeof(float) * N_NODES);
    int*          bsum  = (int*)carve(sizeof(int) * 256);
    u64*          ed2   = (u64*)carve(sizeof(u64) * N_EDGES);
    ushort_t*     ssort = (ushort_t*)carve(sizeof(ushort_t) * E_TOT);
    short*        w1h   = (short*)carve(sizeof(short) * 128 * 256);
    short*        w1l   = (short*)carve(sizeof(short) * 128 * 256);
    short*        w2h   = (short*)carve(sizeof(short) * 256 * 128);
    short*        w2l   = (short*)carve(sizeof(short) * 256 * 128);
    short*        w3h   = (short*)carve(sizeof(short) * 128 * 64);
    short*        w3l   = (short*)carve(sizeof(short) * 128 * 64);
    _Float16*     xh    = (_Float16*)carve(sizeof(_Float16) * (size_t)N_NODES * 128);
    _Float16*     a0h   = (_Float16*)carve(sizeof(_Float16) * (size_t)N_NODES * 128);
    _Float16*     x1h   = (_Float16*)carve(sizeof(_Float16) * (size_t)N_NODES * 256);
    _Float16*     x2h   = (_Float16*)carve(sizeof(_Float16) * (size_t)N_NODES * 128);
    _Float16*     hh    = (_Float16*)carve(sizeof(_Float16) * (size_t)N_NODES * 128);  // h2' then h3'

    (void)hipMemsetAsync(deg, 0, sizeof(int) * N_NODES, stream);
    k_hist<<<(N_EDGES + 255) / 256, 256, 0, stream>>>(srcE, dstE, deg, ed2);
    k_scan1<<<N_NODES / 256, 256, 0, stream>>>(deg, off, bsum);
    k_scan2<<<1, 256, 0, stream>>>(bsum);
    k_scan3<<<N_NODES / 256, 256, 0, stream>>>(deg, off, dis, bsum, ssort);
    k_scatter<<<(N_EDGES + 255) / 256, 256, 0, stream>>>(ed2, off, ssort);
    k_convx<<<(N_NODES * 128 / 4) / 256, 256, 0, stream>>>(x, dis, xh);
    k_convw3<<<(G1 + G2 + G3 + 255) / 256, 256, 0, stream>>>(W1, w1h, w1l, W2, w2h, w2l, W3, w3h, w3l);

    // layer 1 (agg-first): a0[n] = dis[n] * sum xh[src]  (xh pre-scaled by dis[src]), fp16
    k_agg128h<false><<<N_NODES / 4, 256, 0, stream>>>(xh, off, ssort, dis, nullptr, a0h);
    // x1 = softmax(relu(a0@W1 + b1)), fp16
    k_mm<128, 256, true><<<N_NODES / 64, 256, 0, stream>>>(a0h, w1h, w1l, b1, nullptr, x1h);
    // layer 2: h2' = fp16(dis .* (x1@W2)); x2 = softmax(relu(dis[n]*segsum(h2') + b2)), fp16
    k_mm<256, 128, false><<<N_NODES / 64, 256, 0, stream>>>(x1h, w2h, w2l, nullptr, dis, hh);
    k_agg128h<true><<<N_NODES / 4, 256, 0, stream>>>(hh, off, ssort, dis, b2, x2h);
    // layer 3: h3' = fp16(dis .* (x2@W3)); out = softmax(relu(dis[n]*segsum(h3') + b3)), fp32
    k_mm<128, 64, false><<<N_NODES / 64, 256, 0, stream>>>(x2h, w3h, w3l, nullptr, dis, hh);
    k_agg64h<<<N_NODES / 4, 256, 0, stream>>>(hh, off, ssort, dis, b3, (float*)d_out);
}